// Round 1
// baseline (1465.834 us; speedup 1.0000x reference)
//
#include <hip/hip_runtime.h>
#include <hip/hip_bf16.h>

#define N_NODES 100000
#define N_EDGES 1600000
#define D 64

// ---------------------------------------------------------------------------
// Kernel 1: SPMM scatter-add.  AH[row[e]] += vals[e] * H[col[e]]
// One thread handles 4 consecutive d's (float4 gather) of one edge.
// 16 threads per edge -> consecutive threads read the same row/col/val (L1
// broadcast) and gather a contiguous 256B row of H (coalesced).
// ---------------------------------------------------------------------------
__global__ void spmm_atomic_kernel(const int* __restrict__ row,
                                   const int* __restrict__ col,
                                   const float* __restrict__ vals,
                                   const float* __restrict__ H,
                                   float* __restrict__ AH) {
    const long long total = (long long)N_EDGES * 16;  // 16 threads/edge
    long long idx = (long long)blockIdx.x * blockDim.x + threadIdx.x;
    if (idx >= total) return;
    const int e   = (int)(idx >> 4);
    const int sub = (int)(idx & 15);          // which float4 of the row
    const int r   = row[e];
    const int c   = col[e];
    const float v = vals[e];
    const float4 h = *reinterpret_cast<const float4*>(&H[(long long)c * D + sub * 4]);
    float* dst = &AH[(long long)r * D + sub * 4];
    atomicAdd(dst + 0, v * h.x);
    atomicAdd(dst + 1, v * h.y);
    atomicAdd(dst + 2, v * h.z);
    atomicAdd(dst + 3, v * h.w);
}

// ---------------------------------------------------------------------------
// Kernel 2: fused epilogue, in-place on AH (=d_out).
//   support = (1-alpha)*AH + alpha*H0
//   out     = (1-beta)*support + beta*(support @ W)
// One wave (64 lanes) per row; lane d owns column d. Row-dot via shuffle
// broadcast of support[k] against W[k][d] staged in LDS.
// ---------------------------------------------------------------------------
__global__ void __launch_bounds__(256)
gcnii_epilogue_kernel(float* __restrict__ AH_out,
                      const float* __restrict__ H0,
                      const float* __restrict__ W,
                      const float* __restrict__ lamda_p,
                      const float* __restrict__ alpha_p,
                      const int* __restrict__ l_p) {
    __shared__ float Wlds[D * D];  // 16 KB
    // cooperative load of W (4096 floats by 256 threads)
    for (int i = threadIdx.x; i < D * D; i += 256)
        Wlds[i] = W[i];
    __syncthreads();

    const float alpha = alpha_p[0];
    const float lamda = lamda_p[0];
    const float beta  = logf(lamda / (float)l_p[0] + 1.0f);

    const int wave = threadIdx.x >> 6;          // 0..3
    const int lane = threadIdx.x & 63;          // d index
    const int r = blockIdx.x * 4 + wave;
    if (r >= N_NODES) return;

    const long long base = (long long)r * D;
    const float sup = (1.0f - alpha) * AH_out[base + lane] + alpha * H0[base + lane];

    float acc = 0.0f;
    #pragma unroll
    for (int k = 0; k < D; ++k) {
        const float sk = __shfl(sup, k, 64);
        acc = fmaf(sk, Wlds[k * D + lane], acc);
    }
    AH_out[base + lane] = (1.0f - beta) * sup + beta * acc;
}

extern "C" void kernel_launch(void* const* d_in, const int* in_sizes, int n_in,
                              void* d_out, int out_size, void* d_ws, size_t ws_size,
                              hipStream_t stream) {
    const int*   row   = (const int*)  d_in[0];
    const int*   col   = (const int*)  d_in[1];
    const float* vals  = (const float*)d_in[2];
    const float* H     = (const float*)d_in[3];
    const float* H0    = (const float*)d_in[4];
    const float* W     = (const float*)d_in[5];
    const float* lamda = (const float*)d_in[6];
    const float* alpha = (const float*)d_in[7];
    const int*   l     = (const int*)  d_in[8];

    float* out = (float*)d_out;

    // zero the AH accumulator (accumulated in d_out)
    hipMemsetAsync(out, 0, (size_t)out_size * sizeof(float), stream);

    // SPMM scatter-add
    {
        const long long total = (long long)N_EDGES * 16;
        const int block = 256;
        const int grid = (int)((total + block - 1) / block);
        spmm_atomic_kernel<<<grid, block, 0, stream>>>(row, col, vals, H, out);
    }

    // fused support + matmul epilogue (in-place)
    {
        const int block = 256;                   // 4 waves -> 4 rows/block
        const int grid = (N_NODES + 3) / 4;
        gcnii_epilogue_kernel<<<grid, block, 0, stream>>>(out, H0, W, lamda, alpha, l);
    }
}

// Round 2
// 355.806 us; speedup vs baseline: 4.1198x; 4.1198x over previous
//
#include <hip/hip_runtime.h>
#include <hip/hip_bf16.h>

#define N_NODES 100000
#define N_EDGES 1600000
#define D 64
#define CHUNK 1024
#define NCHUNK ((N_NODES + CHUNK - 1) / CHUNK)   // 98

// ===========================================================================
// CSR-build path (no f32 atomics in the hot loop)
// ===========================================================================

// --- 1. histogram of row indices -------------------------------------------
__global__ void hist_kernel(const int* __restrict__ row, int* __restrict__ counts) {
    int e = blockIdx.x * blockDim.x + threadIdx.x;
    if (e >= N_EDGES) return;
    atomicAdd(&counts[row[e]], 1);
}

// --- 2a. per-chunk exclusive scan ------------------------------------------
__global__ void __launch_bounds__(256)
scan1_kernel(const int* __restrict__ counts, int* __restrict__ row_ptr,
             int* __restrict__ chunkTotals) {
    __shared__ int s[256];
    const int t = threadIdx.x;
    const int base = blockIdx.x * CHUNK + t * 4;
    int c0 = (base + 0 < N_NODES) ? counts[base + 0] : 0;
    int c1 = (base + 1 < N_NODES) ? counts[base + 1] : 0;
    int c2 = (base + 2 < N_NODES) ? counts[base + 2] : 0;
    int c3 = (base + 3 < N_NODES) ? counts[base + 3] : 0;
    const int sum = c0 + c1 + c2 + c3;
    s[t] = sum;
    __syncthreads();
    for (int off = 1; off < 256; off <<= 1) {
        int u = (t >= off) ? s[t - off] : 0;
        __syncthreads();
        s[t] += u;
        __syncthreads();
    }
    const int excl = s[t] - sum;  // exclusive prefix within chunk
    if (base + 0 < N_NODES) row_ptr[base + 0] = excl;
    if (base + 1 < N_NODES) row_ptr[base + 1] = excl + c0;
    if (base + 2 < N_NODES) row_ptr[base + 2] = excl + c0 + c1;
    if (base + 3 < N_NODES) row_ptr[base + 3] = excl + c0 + c1 + c2;
    if (t == 255) chunkTotals[blockIdx.x] = s[255];
}

// --- 2b. add inter-chunk offsets; init cursor ------------------------------
__global__ void __launch_bounds__(256)
scan2_kernel(int* __restrict__ row_ptr, int* __restrict__ cursor,
             const int* __restrict__ chunkTotals) {
    int offset = 0;
    for (int i = 0; i < (int)blockIdx.x; ++i) offset += chunkTotals[i];
    const int idx = blockIdx.x * CHUNK + threadIdx.x * 4;
    #pragma unroll
    for (int j = 0; j < 4; ++j) {
        const int k = idx + j;
        if (k < N_NODES) {
            const int v = row_ptr[k] + offset;
            row_ptr[k] = v;
            cursor[k]  = v;
        }
    }
    if (blockIdx.x == 0 && threadIdx.x == 0) row_ptr[N_NODES] = N_EDGES;
}

// --- 3. scatter edges into row-sorted order --------------------------------
__global__ void scatter_kernel(const int* __restrict__ row, const int* __restrict__ col,
                               const float* __restrict__ vals,
                               int* __restrict__ cursor,
                               int* __restrict__ scol, float* __restrict__ sval) {
    int e = blockIdx.x * blockDim.x + threadIdx.x;
    if (e >= N_EDGES) return;
    const int pos = atomicAdd(&cursor[row[e]], 1);
    scol[pos] = col[e];
    sval[pos] = vals[e];
}

// --- 4. fused gather-SPMM + GCNII epilogue ---------------------------------
// One wave per row; lane d owns column d. AH accumulates in a register; then
//   support = (1-a)*AH + a*H0;  out = (1-b)*support + b*(support @ W)
__global__ void __launch_bounds__(256)
gather_fused_kernel(const int* __restrict__ row_ptr,
                    const int* __restrict__ scol, const float* __restrict__ sval,
                    const float* __restrict__ H, const float* __restrict__ H0,
                    const float* __restrict__ W,
                    const float* __restrict__ lamda_p, const float* __restrict__ alpha_p,
                    const int* __restrict__ l_p,
                    float* __restrict__ out) {
    __shared__ float Wlds[D * D];  // 16 KB
    for (int i = threadIdx.x; i < D * D; i += 256) Wlds[i] = W[i];
    __syncthreads();

    const float alpha = alpha_p[0];
    const float beta  = logf(lamda_p[0] / (float)l_p[0] + 1.0f);

    const int wave = threadIdx.x >> 6;
    const int lane = threadIdx.x & 63;
    const int r = blockIdx.x * 4 + wave;
    if (r >= N_NODES) return;

    const int start = row_ptr[r];
    const int end   = row_ptr[r + 1];

    float acc = 0.0f, acc2 = 0.0f;
    int e = start;
    for (; e + 1 < end; e += 2) {
        const int   c0 = scol[e],     c1 = scol[e + 1];
        const float v0 = sval[e],     v1 = sval[e + 1];
        acc  = fmaf(v0, H[(long long)c0 * D + lane], acc);
        acc2 = fmaf(v1, H[(long long)c1 * D + lane], acc2);
    }
    if (e < end)
        acc = fmaf(sval[e], H[(long long)scol[e] * D + lane], acc);
    acc += acc2;

    const long long base = (long long)r * D;
    const float sup = (1.0f - alpha) * acc + alpha * H0[base + lane];

    float dot = 0.0f;
    #pragma unroll
    for (int k = 0; k < D; ++k)
        dot = fmaf(__shfl(sup, k, 64), Wlds[k * D + lane], dot);

    out[base + lane] = (1.0f - beta) * sup + beta * dot;
}

// ===========================================================================
// Fallback path (round-1): f32 atomic scatter + separate epilogue
// ===========================================================================
__global__ void spmm_atomic_kernel(const int* __restrict__ row,
                                   const int* __restrict__ col,
                                   const float* __restrict__ vals,
                                   const float* __restrict__ H,
                                   float* __restrict__ AH) {
    const long long total = (long long)N_EDGES * 16;
    long long idx = (long long)blockIdx.x * blockDim.x + threadIdx.x;
    if (idx >= total) return;
    const int e   = (int)(idx >> 4);
    const int sub = (int)(idx & 15);
    const int r   = row[e];
    const int c   = col[e];
    const float v = vals[e];
    const float4 h = *reinterpret_cast<const float4*>(&H[(long long)c * D + sub * 4]);
    float* dst = &AH[(long long)r * D + sub * 4];
    atomicAdd(dst + 0, v * h.x);
    atomicAdd(dst + 1, v * h.y);
    atomicAdd(dst + 2, v * h.z);
    atomicAdd(dst + 3, v * h.w);
}

__global__ void __launch_bounds__(256)
gcnii_epilogue_kernel(float* __restrict__ AH_out,
                      const float* __restrict__ H0,
                      const float* __restrict__ W,
                      const float* __restrict__ lamda_p,
                      const float* __restrict__ alpha_p,
                      const int* __restrict__ l_p) {
    __shared__ float Wlds[D * D];
    for (int i = threadIdx.x; i < D * D; i += 256) Wlds[i] = W[i];
    __syncthreads();
    const float alpha = alpha_p[0];
    const float beta  = logf(lamda_p[0] / (float)l_p[0] + 1.0f);
    const int wave = threadIdx.x >> 6;
    const int lane = threadIdx.x & 63;
    const int r = blockIdx.x * 4 + wave;
    if (r >= N_NODES) return;
    const long long base = (long long)r * D;
    const float sup = (1.0f - alpha) * AH_out[base + lane] + alpha * H0[base + lane];
    float acc = 0.0f;
    #pragma unroll
    for (int k = 0; k < D; ++k)
        acc = fmaf(__shfl(sup, k, 64), Wlds[k * D + lane], acc);
    AH_out[base + lane] = (1.0f - beta) * sup + beta * acc;
}

// ===========================================================================
extern "C" void kernel_launch(void* const* d_in, const int* in_sizes, int n_in,
                              void* d_out, int out_size, void* d_ws, size_t ws_size,
                              hipStream_t stream) {
    const int*   row   = (const int*)  d_in[0];
    const int*   col   = (const int*)  d_in[1];
    const float* vals  = (const float*)d_in[2];
    const float* H     = (const float*)d_in[3];
    const float* H0    = (const float*)d_in[4];
    const float* W     = (const float*)d_in[5];
    const float* lamda = (const float*)d_in[6];
    const float* alpha = (const float*)d_in[7];
    const int*   l     = (const int*)  d_in[8];
    float* out = (float*)d_out;

    // workspace layout (ints/floats, all 4B):
    //   counts/cursor : [0, N)            -- cursor reuses counts? no: separate
    //   counts  : [0, 100000)
    //   row_ptr : [100000, 200001)
    //   cursor  : [200064, 300064)
    //   totals  : [300064, 300192)
    //   scol    : [300192, 1900192)
    //   sval    : [1900192, 3500192)
    const size_t needed = (size_t)3500192 * 4;
    if (ws_size >= needed) {
        int*   counts  = (int*)d_ws;
        int*   row_ptr = counts + 100000;
        int*   cursor  = counts + 200064;
        int*   totals  = counts + 300064;
        int*   scol    = counts + 300192;
        float* sval    = (float*)(counts + 1900192);

        hipMemsetAsync(counts, 0, (size_t)N_NODES * sizeof(int), stream);
        hist_kernel<<<(N_EDGES + 255) / 256, 256, 0, stream>>>(row, counts);
        scan1_kernel<<<NCHUNK, 256, 0, stream>>>(counts, row_ptr, totals);
        scan2_kernel<<<NCHUNK, 256, 0, stream>>>(row_ptr, cursor, totals);
        scatter_kernel<<<(N_EDGES + 255) / 256, 256, 0, stream>>>(row, col, vals,
                                                                  cursor, scol, sval);
        gather_fused_kernel<<<(N_NODES + 3) / 4, 256, 0, stream>>>(
            row_ptr, scol, sval, H, H0, W, lamda, alpha, l, out);
    } else {
        // fallback: round-1 atomic path
        hipMemsetAsync(out, 0, (size_t)out_size * sizeof(float), stream);
        const long long total = (long long)N_EDGES * 16;
        spmm_atomic_kernel<<<(int)((total + 255) / 256), 256, 0, stream>>>(row, col, vals, H, out);
        gcnii_epilogue_kernel<<<(N_NODES + 3) / 4, 256, 0, stream>>>(out, H0, W,
                                                                     lamda, alpha, l);
    }
}

// Round 3
// 349.480 us; speedup vs baseline: 4.1943x; 1.0181x over previous
//
#include <hip/hip_runtime.h>
#include <hip/hip_bf16.h>

#define N_NODES 100000
#define N_EDGES 1600000
#define D 64
#define CHUNK 1024
#define NCHUNK ((N_NODES + CHUNK - 1) / CHUNK)   // 98

// ===========================================================================
// CSR-build path (no f32 atomics anywhere)
// ===========================================================================

// --- 1. histogram of row indices -------------------------------------------
__global__ void hist_kernel(const int* __restrict__ row, int* __restrict__ counts) {
    int e = blockIdx.x * blockDim.x + threadIdx.x;
    if (e >= N_EDGES) return;
    atomicAdd(&counts[row[e]], 1);
}

// --- 2a. per-chunk exclusive scan ------------------------------------------
__global__ void __launch_bounds__(256)
scan1_kernel(const int* __restrict__ counts, int* __restrict__ row_ptr,
             int* __restrict__ chunkTotals) {
    __shared__ int s[256];
    const int t = threadIdx.x;
    const int base = blockIdx.x * CHUNK + t * 4;
    int c0 = (base + 0 < N_NODES) ? counts[base + 0] : 0;
    int c1 = (base + 1 < N_NODES) ? counts[base + 1] : 0;
    int c2 = (base + 2 < N_NODES) ? counts[base + 2] : 0;
    int c3 = (base + 3 < N_NODES) ? counts[base + 3] : 0;
    const int sum = c0 + c1 + c2 + c3;
    s[t] = sum;
    __syncthreads();
    for (int off = 1; off < 256; off <<= 1) {
        int u = (t >= off) ? s[t - off] : 0;
        __syncthreads();
        s[t] += u;
        __syncthreads();
    }
    const int excl = s[t] - sum;
    if (base + 0 < N_NODES) row_ptr[base + 0] = excl;
    if (base + 1 < N_NODES) row_ptr[base + 1] = excl + c0;
    if (base + 2 < N_NODES) row_ptr[base + 2] = excl + c0 + c1;
    if (base + 3 < N_NODES) row_ptr[base + 3] = excl + c0 + c1 + c2;
    if (t == 255) chunkTotals[blockIdx.x] = s[255];
}

// --- 2b. add inter-chunk offsets; init cursor ------------------------------
__global__ void __launch_bounds__(256)
scan2_kernel(int* __restrict__ row_ptr, int* __restrict__ cursor,
             const int* __restrict__ chunkTotals) {
    int offset = 0;
    for (int i = 0; i < (int)blockIdx.x; ++i) offset += chunkTotals[i];
    const int idx = blockIdx.x * CHUNK + threadIdx.x * 4;
    #pragma unroll
    for (int j = 0; j < 4; ++j) {
        const int k = idx + j;
        if (k < N_NODES) {
            const int v = row_ptr[k] + offset;
            row_ptr[k] = v;
            cursor[k]  = v;
        }
    }
    if (blockIdx.x == 0 && threadIdx.x == 0) row_ptr[N_NODES] = N_EDGES;
}

// --- 3. scatter edges into row-sorted order, packed (col,val) --------------
__global__ void scatter_kernel(const int* __restrict__ row, const int* __restrict__ col,
                               const float* __restrict__ vals,
                               int* __restrict__ cursor,
                               uint2* __restrict__ epack) {
    int e = blockIdx.x * blockDim.x + threadIdx.x;
    if (e >= N_EDGES) return;
    const int pos = atomicAdd(&cursor[row[e]], 1);
    epack[pos] = make_uint2((unsigned)col[e], __float_as_uint(vals[e]));
}

// --- 4. fused gather-SPMM + GCNII epilogue ---------------------------------
// One wave per row; lane d owns column d. Per 16-edge chunk, lanes 0..15 load
// packed (col,val) with one coalesced load; k-loop broadcasts via shuffle and
// issues 16 independent H-row gathers (high MLP). Then:
//   support = (1-a)*AH + a*H0;  out = (1-b)*support + b*(support @ W)
__global__ void __launch_bounds__(256)
gather_fused_kernel(const int* __restrict__ row_ptr,
                    const uint2* __restrict__ epack,
                    const float* __restrict__ H, const float* __restrict__ H0,
                    const float* __restrict__ W,
                    const float* __restrict__ lamda_p, const float* __restrict__ alpha_p,
                    const int* __restrict__ l_p,
                    float* __restrict__ out) {
    __shared__ float Wlds[D * D];  // 16 KB
    for (int i = threadIdx.x; i < D * D; i += 256) Wlds[i] = W[i];
    __syncthreads();

    const float alpha = alpha_p[0];
    const float beta  = logf(lamda_p[0] / (float)l_p[0] + 1.0f);

    const int wave = threadIdx.x >> 6;
    const int lane = threadIdx.x & 63;
    const int r = blockIdx.x * 4 + wave;
    if (r >= N_NODES) return;

    const int start = row_ptr[r];
    const int end   = row_ptr[r + 1];
    const int lm    = lane & 15;

    float a0 = 0.f, a1 = 0.f, a2 = 0.f, a3 = 0.f;

    int e = start;
    for (; e + 16 <= end; e += 16) {
        const uint2 ed = epack[e + lm];   // 16-lane groups each read same 128B
        #pragma unroll
        for (int k = 0; k < 16; ++k) {
            const int   c = __shfl((int)ed.x, k, 64);
            const float v = __shfl(__uint_as_float(ed.y), k, 64);
            const float h = H[(size_t)c * D + lane];
            if ((k & 3) == 0) a0 = fmaf(v, h, a0);
            else if ((k & 3) == 1) a1 = fmaf(v, h, a1);
            else if ((k & 3) == 2) a2 = fmaf(v, h, a2);
            else a3 = fmaf(v, h, a3);
        }
    }
    const int rem = end - e;
    if (rem > 0) {
        const uint2 ed = (lm < rem) ? epack[e + lm] : make_uint2(0u, 0u);
        for (int k = 0; k < rem; ++k) {
            const int   c = __shfl((int)ed.x, k, 64);
            const float v = __shfl(__uint_as_float(ed.y), k, 64);
            a0 = fmaf(v, H[(size_t)c * D + lane], a0);
        }
    }
    const float acc = (a0 + a1) + (a2 + a3);

    const long long base = (long long)r * D;
    const float sup = (1.0f - alpha) * acc + alpha * H0[base + lane];

    float dot = 0.0f;
    #pragma unroll
    for (int k = 0; k < D; ++k)
        dot = fmaf(__shfl(sup, k, 64), Wlds[k * D + lane], dot);

    out[base + lane] = (1.0f - beta) * sup + beta * dot;
}

// ===========================================================================
// Fallback path (round-1): f32 atomic scatter + separate epilogue
// ===========================================================================
__global__ void spmm_atomic_kernel(const int* __restrict__ row,
                                   const int* __restrict__ col,
                                   const float* __restrict__ vals,
                                   const float* __restrict__ H,
                                   float* __restrict__ AH) {
    const long long total = (long long)N_EDGES * 16;
    long long idx = (long long)blockIdx.x * blockDim.x + threadIdx.x;
    if (idx >= total) return;
    const int e   = (int)(idx >> 4);
    const int sub = (int)(idx & 15);
    const int r   = row[e];
    const int c   = col[e];
    const float v = vals[e];
    const float4 h = *reinterpret_cast<const float4*>(&H[(long long)c * D + sub * 4]);
    float* dst = &AH[(long long)r * D + sub * 4];
    atomicAdd(dst + 0, v * h.x);
    atomicAdd(dst + 1, v * h.y);
    atomicAdd(dst + 2, v * h.z);
    atomicAdd(dst + 3, v * h.w);
}

__global__ void __launch_bounds__(256)
gcnii_epilogue_kernel(float* __restrict__ AH_out,
                      const float* __restrict__ H0,
                      const float* __restrict__ W,
                      const float* __restrict__ lamda_p,
                      const float* __restrict__ alpha_p,
                      const int* __restrict__ l_p) {
    __shared__ float Wlds[D * D];
    for (int i = threadIdx.x; i < D * D; i += 256) Wlds[i] = W[i];
    __syncthreads();
    const float alpha = alpha_p[0];
    const float beta  = logf(lamda_p[0] / (float)l_p[0] + 1.0f);
    const int wave = threadIdx.x >> 6;
    const int lane = threadIdx.x & 63;
    const int r = blockIdx.x * 4 + wave;
    if (r >= N_NODES) return;
    const long long base = (long long)r * D;
    const float sup = (1.0f - alpha) * AH_out[base + lane] + alpha * H0[base + lane];
    float acc = 0.0f;
    #pragma unroll
    for (int k = 0; k < D; ++k)
        acc = fmaf(__shfl(sup, k, 64), Wlds[k * D + lane], acc);
    AH_out[base + lane] = (1.0f - beta) * sup + beta * acc;
}

// ===========================================================================
extern "C" void kernel_launch(void* const* d_in, const int* in_sizes, int n_in,
                              void* d_out, int out_size, void* d_ws, size_t ws_size,
                              hipStream_t stream) {
    const int*   row   = (const int*)  d_in[0];
    const int*   col   = (const int*)  d_in[1];
    const float* vals  = (const float*)d_in[2];
    const float* H     = (const float*)d_in[3];
    const float* H0    = (const float*)d_in[4];
    const float* W     = (const float*)d_in[5];
    const float* lamda = (const float*)d_in[6];
    const float* alpha = (const float*)d_in[7];
    const int*   l     = (const int*)  d_in[8];
    float* out = (float*)d_out;

    // workspace layout (4B words):
    //   counts  : [0, 100000)
    //   row_ptr : [100000, 200001)
    //   cursor  : [200064, 300064)
    //   totals  : [300064, 300192)
    //   epack   : [300192, 3500192)   (uint2; byte offset 1200768 % 8 == 0)
    const size_t needed = (size_t)3500192 * 4;
    if (ws_size >= needed) {
        int*   counts  = (int*)d_ws;
        int*   row_ptr = counts + 100000;
        int*   cursor  = counts + 200064;
        int*   totals  = counts + 300064;
        uint2* epack   = (uint2*)(counts + 300192);

        hipMemsetAsync(counts, 0, (size_t)N_NODES * sizeof(int), stream);
        hist_kernel<<<(N_EDGES + 255) / 256, 256, 0, stream>>>(row, counts);
        scan1_kernel<<<NCHUNK, 256, 0, stream>>>(counts, row_ptr, totals);
        scan2_kernel<<<NCHUNK, 256, 0, stream>>>(row_ptr, cursor, totals);
        scatter_kernel<<<(N_EDGES + 255) / 256, 256, 0, stream>>>(row, col, vals,
                                                                  cursor, epack);
        gather_fused_kernel<<<(N_NODES + 3) / 4, 256, 0, stream>>>(
            row_ptr, epack, H, H0, W, lamda, alpha, l, out);
    } else {
        // fallback: round-1 atomic path
        hipMemsetAsync(out, 0, (size_t)out_size * sizeof(float), stream);
        const long long total = (long long)N_EDGES * 16;
        spmm_atomic_kernel<<<(int)((total + 255) / 256), 256, 0, stream>>>(row, col, vals, H, out);
        gcnii_epilogue_kernel<<<(N_NODES + 3) / 4, 256, 0, stream>>>(out, H0, W,
                                                                     lamda, alpha, l);
    }
}